// Round 19
// baseline (104.040 us; speedup 1.0000x reference)
//
#include <hip/hip_runtime.h>
#include <hip/hip_bf16.h>
#include <stdint.h>

#define B_ 16
#define S_ 2048
#define D_ 512
#define A_ 512

typedef __attribute__((ext_vector_type(4))) float f32x4;
typedef __attribute__((ext_vector_type(8))) short bf16x8;

__device__ inline unsigned short f2bf(float f) {
  union { float f; unsigned int u; } c; c.f = f;
  unsigned int u = c.u;
  unsigned int r = (u + 0x7fffu + ((u >> 16) & 1u)) >> 16;  // RNE
  return (unsigned short)r;
}

__device__ inline unsigned pk2bf(float x, float y) {
  __hip_bfloat162 p = __float22bfloat162_rn(float2{x, y});
  union { __hip_bfloat162 h; unsigned u; } c; c.h = p;
  return c.u;
}

__device__ inline float fast_tanh(float x) {
  float e = __expf(2.0f * x);
  return 1.0f - 2.0f * __builtin_amdgcn_rcpf(e + 1.0f);
}

__device__ inline void gload_lds16(const void* g, void* l) {
  __builtin_amdgcn_global_load_lds((const __attribute__((address_space(1))) void*)g,
                                   (__attribute__((address_space(3))) void*)l, 16, 0, 0);
}

// ---------------------------------------------------------------------------
// K0: pack [Wq;Wk] (each [512,512] f32, row=d, col=a) into WT bf16
// [A=512][Kcat=1024] (row=a, col=d-concat), i.e. B^T layout for the GEMM.
// ---------------------------------------------------------------------------
__global__ __launch_bounds__(256) void k0_pack_w(const float* __restrict__ Wq,
                                                 const float* __restrict__ Wk,
                                                 unsigned short* __restrict__ WT) {
  __shared__ unsigned short tile[64][65];
  int bid = blockIdx.x;
  int dt = bid & 15, at = bid >> 4;
  int d0 = dt * 64, a0 = at * 64;
  int t = threadIdx.x;
  int col = t & 63, rbase = t >> 6;
#pragma unroll
  for (int r8 = 0; r8 < 16; ++r8) {
    int row = r8 * 4 + rbase;
    int dcat = d0 + row;
    float f = (dcat < 512) ? Wq[(size_t)dcat * 512 + a0 + col]
                           : Wk[(size_t)(dcat - 512) * 512 + a0 + col];
    tile[row][col] = f2bf(f);
  }
  __syncthreads();
#pragma unroll
  for (int r8 = 0; r8 < 16; ++r8) {
    int arow = r8 * 4 + rbase;
    WT[(size_t)(a0 + arow) * 1024 + d0 + col] = tile[col][arow];
  }
}

// ---------------------------------------------------------------------------
// K1: scores — ALL-DMA staging (m97-pure). BM=128, BN=512, BK=32, 32 phases,
// 512 threads = 8 waves, wave-tile 128x64 (8x4 frags, acc=128).
// CHANGE vs r10: A is staged as RAW FP32 via global_load_lds (DMA engine) —
// no vector-load returns, no reg round-trip, no ds_write by compute waves
// (the r9-vs-m97 gap isolates this chain as the structural drag). fp32->bf16
// conversion moves AFTER the fragment ds_read (8 cvt_pk/frag, pure VALU
// between ds_read and MFMA — the position r10 proved cheap).
// A LDS: fp32 [128][32], 128B rows, 8x16B chunks, slot c holds global chunk
// c ^ (row&7) (per-lane pre-swizzled gload source, LDS linear — rule #21).
// B path r10-verbatim (bf16, 64B rows, chunk ^ ((row>>1)&3)).
// Phase p: stageA(p+1)+stageB(p+1) into buf^1 (6 gloads/thread, DMA) |
//          frags(p)+cvt+32 MFMA | vmcnt(0) lgkm(0) | s_barrier.
// DMA(p+1) rides under compute(p) via the dbuf; drain at phase end is
// covered (DMA 48 KB ~2200cy ~= compute).
// ---------------------------------------------------------------------------
__global__ __launch_bounds__(512, 2) void k1_scores(
    const float* __restrict__ Q, const float* __restrict__ K,
    const unsigned short* __restrict__ WT, const float* __restrict__ Wsv,
    float* __restrict__ score) {
  __shared__ float Af[2][128 * 32];            // 2 x 16 KiB (fp32 A)
  __shared__ unsigned short Bl[2][512 * 32];   // 2 x 32 KiB (bf16 B)
  __shared__ float scw[8][128];                // 4 KiB

  const int t = threadIdx.x;
  const int lane = t & 63, w = t >> 6;
  const int frow = lane & 15, fsl = lane >> 4;
  const int row0 = (int)blockIdx.x * 128;

  auto stageA = [&](int p, int buf) {
    const float* src = (p < 16) ? Q : K;
    int kk = (p * 32) & 511;
#pragma unroll
    for (int q = 0; q < 2; ++q) {
      int pc = w * 128 + q * 64 + lane;        // 16B chunk 0..1023
      int row = pc >> 3, c = pc & 7;
      int gc = c ^ (row & 7);                  // pre-swizzled source chunk
      const float* g = src + (size_t)(row0 + row) * 512 + kk + gc * 4;
      gload_lds16(g, (char*)&Af[buf][0] + (size_t)(w * 128 + q * 64) * 16);
    }
  };
  auto stageB = [&](int p, int buf) {
#pragma unroll
    for (int q = 0; q < 4; ++q) {
      int pc = (w * 4 + q) * 64 + lane;        // 16B-chunk index
      int row = pc >> 2;
      int sl = (pc & 3) ^ ((row >> 1) & 3);    // inverse-swizzled source slot
      const char* g = (const char*)WT + (size_t)row * 2048 + p * 64 + sl * 16;
      gload_lds16(g, (char*)&Bl[buf][0] + (size_t)(w * 4 + q) * 1024);
    }
  };

  f32x4 acc[8][4];
#pragma unroll
  for (int m = 0; m < 8; ++m)
#pragma unroll
    for (int n = 0; n < 4; ++n) acc[m][n] = (f32x4){0.f, 0.f, 0.f, 0.f};

  const int chB = (fsl ^ ((frow >> 1) & 3)) * 16;

  auto doMfma = [&](int CUR) {
    // A fragments: fp32 from LDS (swizzled chunks), cvt_pk -> bf16.
    bf16x8 af[8];
#pragma unroll
    for (int m = 0; m < 8; ++m) {
      int row = m * 16 + frow;
      int c0 = (fsl * 2) ^ (row & 7);
      const float* base = &Af[CUR][row * 32];
      float4 lo = *(const float4*)(base + c0 * 4);
      float4 hi = *(const float4*)(base + (c0 ^ 1) * 4);
      union { bf16x8 v; unsigned u[4]; } cc;
      cc.u[0] = pk2bf(lo.x, lo.y);
      cc.u[1] = pk2bf(lo.z, lo.w);
      cc.u[2] = pk2bf(hi.x, hi.y);
      cc.u[3] = pk2bf(hi.z, hi.w);
      af[m] = cc.v;
    }
    bf16x8 bfr[4];
#pragma unroll
    for (int n = 0; n < 4; ++n)
      bfr[n] = *(const bf16x8*)((const char*)&Bl[CUR][0] + (w * 64 + n * 16 + frow) * 64 + chB);
    __builtin_amdgcn_s_setprio(1);
#pragma unroll
    for (int m = 0; m < 8; ++m)
#pragma unroll
      for (int n = 0; n < 4; ++n)
        acc[m][n] = __builtin_amdgcn_mfma_f32_16x16x32_bf16(af[m], bfr[n], acc[m][n], 0, 0, 0);
    __builtin_amdgcn_s_setprio(0);
  };

  // ---- prologue: tile 0 fully staged via DMA ----
  stageA(0, 0);
  stageB(0, 0);
  asm volatile("s_waitcnt vmcnt(0) lgkmcnt(0)" ::: "memory");
  __builtin_amdgcn_s_barrier();

  // ---- main loop: phases 0..30 (stage p+1 under compute p) ----
  for (int kt = 0; kt < 31; ++kt) {
    const int cur = kt & 1;
    stageA(kt + 1, cur ^ 1);
    stageB(kt + 1, cur ^ 1);
    doMfma(cur);
    asm volatile("s_waitcnt vmcnt(0) lgkmcnt(0)" ::: "memory");
    __builtin_amdgcn_s_barrier();
  }
  // ---- tail: phase 31 (compute only) ----
  doMfma(1);

  // ---- epilogue: tanh * Ws, reduce over all 512 cols ----
  float wsv[4];
#pragma unroll
  for (int n = 0; n < 4; ++n) wsv[n] = Wsv[w * 64 + n * 16 + frow];
#pragma unroll
  for (int m = 0; m < 8; ++m) {
#pragma unroll
    for (int ii = 0; ii < 4; ++ii) {
      float s = 0.f;
#pragma unroll
      for (int n = 0; n < 4; ++n)
        s += fast_tanh(acc[m][n][ii]) * wsv[n];
      s += __shfl_xor(s, 1);
      s += __shfl_xor(s, 2);
      s += __shfl_xor(s, 4);
      s += __shfl_xor(s, 8);
      if (frow == 0) scw[w][m * 16 + fsl * 4 + ii] = s;
    }
  }
  __syncthreads();
  if (t < 128) {
    float s = 0.f;
#pragma unroll
    for (int ww = 0; ww < 8; ++ww) s += scw[ww][t];
    score[row0 + t] = s;
  }
}

// ---------------------------------------------------------------------------
// K3 (fused softmax + V-weighted sum): block (dh, sc, b) re-derives the
// batch softmax from the L2-hot score row, then computes
// upart[sc][b][dh-half]; dh==0 blocks write outw.
// ---------------------------------------------------------------------------
__global__ __launch_bounds__(256) void k3_vsum(const float* __restrict__ value,
                                               const float* __restrict__ score,
                                               float* __restrict__ upart,
                                               float* __restrict__ outw) {
  int bid = blockIdx.x;
  int dh = bid & 1, sc = (bid >> 1) & 15, b = bid >> 5;
  int t = threadIdx.x;
  int lane = t & 63, wave = t >> 6;
  int dg = t & 63, sg = t >> 6;
  __shared__ float red[4], red2[4];
  __shared__ float wl[128];
  __shared__ f32x4 redv[4][64];

  float v[8];
  float mx = -1e30f;
#pragma unroll
  for (int e = 0; e < 8; ++e) {
    float p = score[(size_t)b * S_ + e * 256 + t];
    v[e] = p;
    mx = fmaxf(mx, p);
  }
  for (int off = 1; off < 64; off <<= 1) mx = fmaxf(mx, __shfl_xor(mx, off));
  if (lane == 0) red[wave] = mx;
  __syncthreads();
  mx = fmaxf(fmaxf(red[0], red[1]), fmaxf(red[2], red[3]));
  float sum = 0.f;
#pragma unroll
  for (int e = 0; e < 8; ++e) sum += expf(v[e] - mx);
  for (int off = 1; off < 64; off <<= 1) sum += __shfl_xor(sum, off);
  if (lane == 0) red2[wave] = sum;
  __syncthreads();
  sum = red2[0] + red2[1] + red2[2] + red2[3];
  float inv = 1.f / sum;

  int s0 = sc * 128;
  if (t < 128) {
    size_t o = (size_t)b * S_ + s0 + t;
    float ww = expf(score[o] - mx) * inv;
    wl[t] = ww;
    if (dh == 0) outw[o] = ww;
  }
  __syncthreads();

  const float* vp = value + ((size_t)b * S_ + s0) * 512 + dh * 256 + dg * 4;
  f32x4 a = (f32x4){0.f, 0.f, 0.f, 0.f};
  for (int s = sg; s < 128; s += 4) {
    float4 v4 = *(const float4*)(vp + (size_t)s * 512);
    float ws = wl[s];
    a[0] += ws * v4.x; a[1] += ws * v4.y; a[2] += ws * v4.z; a[3] += ws * v4.w;
  }
  redv[sg][dg] = a;
  __syncthreads();
  if (sg == 0) {
    f32x4 r = redv[0][dg] + redv[1][dg] + redv[2][dg] + redv[3][dg];
    float* dst = upart + (size_t)(sc * 16 + b) * 512 + dh * 256 + dg * 4;
    dst[0] = r[0]; dst[1] = r[1]; dst[2] = r[2]; dst[3] = r[3];
  }
}

// ---------------------------------------------------------------------------
// K4: context[b,a] = sum_d u[b,d] * Wv[d,a]. fp32. 64 blocks.
// ---------------------------------------------------------------------------
__global__ __launch_bounds__(256) void k4_ctx(const float* __restrict__ upart,
                                              const float* __restrict__ Wv,
                                              float* __restrict__ out) {
  int b = blockIdx.x >> 2, q = blockIdx.x & 3;
  int t = threadIdx.x;
  int col = q * 128 + (t & 127), dhf = t >> 7;
  __shared__ float ul[512];
  __shared__ float part[2][128];
  for (int i = t; i < 512; i += 256) {
    float u = 0.f;
#pragma unroll
    for (int c = 0; c < 16; ++c) u += upart[(size_t)(c * 16 + b) * 512 + i];
    ul[i] = u;
  }
  __syncthreads();
  float acc = 0.f;
#pragma unroll 8
  for (int d = dhf * 256; d < dhf * 256 + 256; ++d)
    acc += ul[d] * Wv[(size_t)d * 512 + col];
  part[dhf][t & 127] = acc;
  __syncthreads();
  if (dhf == 0)
    out[(size_t)b * 512 + col] = part[0][t & 127] + part[1][t & 127];
}

// ---------------------------------------------------------------------------
extern "C" void kernel_launch(void* const* d_in, const int* in_sizes, int n_in,
                              void* d_out, int out_size, void* d_ws, size_t ws_size,
                              hipStream_t stream) {
  const float* Q  = (const float*)d_in[0];
  const float* Kk = (const float*)d_in[1];
  const float* V  = (const float*)d_in[2];
  const float* Wq = (const float*)d_in[3];
  const float* Wk = (const float*)d_in[4];
  const float* Wv = (const float*)d_in[5];
  const float* Ws = (const float*)d_in[6];
  float* out = (float*)d_out;

  char* ws = (char*)d_ws;
  unsigned short* WT = (unsigned short*)ws;                        // 1 MiB
  float* score = (float*)(ws + (1 << 20));                         // 128 KiB
  float* upart = (float*)(ws + (1 << 20) + (512 << 10));           // 512 KiB

  float* outw = out + B_ * A_;   // attention weights region [B*S]

  k0_pack_w<<<dim3(128), dim3(256), 0, stream>>>(Wq, Wk, WT);
  k1_scores<<<dim3(256), dim3(512), 0, stream>>>(Q, Kk, WT, Ws, score);
  k3_vsum<<<dim3(512), dim3(256), 0, stream>>>(V, score, upart, outw);
  k4_ctx<<<dim3(64), dim3(256), 0, stream>>>(upart, Wv, out);
}

// Round 21
// 87.888 us; speedup vs baseline: 1.1838x; 1.1838x over previous
//
#include <hip/hip_runtime.h>
#include <hip/hip_bf16.h>
#include <stdint.h>

#define B_ 16
#define S_ 2048
#define D_ 512
#define A_ 512

typedef __attribute__((ext_vector_type(4))) float f32x4;
typedef __attribute__((ext_vector_type(8))) short bf16x8;

__device__ inline unsigned short f2bf(float f) {
  union { float f; unsigned int u; } c; c.f = f;
  unsigned int u = c.u;
  unsigned int r = (u + 0x7fffu + ((u >> 16) & 1u)) >> 16;  // RNE
  return (unsigned short)r;
}

__device__ inline unsigned pk2bf(float x, float y) {
  __hip_bfloat162 p = __float22bfloat162_rn(float2{x, y});
  union { __hip_bfloat162 h; unsigned u; } c; c.h = p;
  return c.u;
}

__device__ inline float fast_tanh(float x) {
  float e = __expf(2.0f * x);
  return 1.0f - 2.0f * __builtin_amdgcn_rcpf(e + 1.0f);
}

__device__ inline void gload_lds16(const void* g, void* l) {
  __builtin_amdgcn_global_load_lds((const __attribute__((address_space(1))) void*)g,
                                   (__attribute__((address_space(3))) void*)l, 16, 0, 0);
}

// ---------------------------------------------------------------------------
// K0: pack [Wq;Wk] (each [512,512] f32, row=d, col=a) into WT bf16
// [A=512][Kcat=1024] (row=a, col=d-concat), i.e. B^T layout for the GEMM.
// ---------------------------------------------------------------------------
__global__ __launch_bounds__(256) void k0_pack_w(const float* __restrict__ Wq,
                                                 const float* __restrict__ Wk,
                                                 unsigned short* __restrict__ WT) {
  __shared__ unsigned short tile[64][65];
  int bid = blockIdx.x;
  int dt = bid & 15, at = bid >> 4;
  int d0 = dt * 64, a0 = at * 64;
  int t = threadIdx.x;
  int col = t & 63, rbase = t >> 6;
#pragma unroll
  for (int r8 = 0; r8 < 16; ++r8) {
    int row = r8 * 4 + rbase;
    int dcat = d0 + row;
    float f = (dcat < 512) ? Wq[(size_t)dcat * 512 + a0 + col]
                           : Wk[(size_t)(dcat - 512) * 512 + a0 + col];
    tile[row][col] = f2bf(f);
  }
  __syncthreads();
#pragma unroll
  for (int r8 = 0; r8 < 16; ++r8) {
    int arow = r8 * 4 + rbase;
    WT[(size_t)(a0 + arow) * 1024 + d0 + col] = tile[col][arow];
  }
}

// ---------------------------------------------------------------------------
// K1: scores — r10 per-step machinery VERBATIM, TWO K-steps per barrier
// period (16 periods instead of 32: tests the ~2-3k cy fixed per-period
// cost). CORRECTED vs r20: the four A register pairs are separate named
// arrays passed as distinct float4* arguments — no cross-array aliasing,
// nothing address-taken (rule #20; r20's (float4(*)[2])&rA0 cast sent the
// pairs to scratch with undefined layout -> absmax 0.075).
// 4 LDS slots = 2 period-buffers x 2 sub-steps; period i computes steps
// {2i,2i+1} from slots {(i&1)*2,+1}, stages B(2i+2),B(2i+3) into the other
// pair, issues A(2i+4),A(2i+5) that stay in flight across the barrier
// (vmcnt(4) = drain the 8 B-DMAs, keep the 4 A-loads).
// BM=128, BN=512, BK=32/step, 512 threads = 8 waves, wave-tile 128x64.
// LDS = 4x(8+32) KiB = 160 KiB (1 block/CU — grid was already the
// occupancy limiter). All swizzles/addresses r10-proven.
// ---------------------------------------------------------------------------
__global__ __launch_bounds__(512, 1) void k1_scores(
    const float* __restrict__ Q, const float* __restrict__ K,
    const unsigned short* __restrict__ WT, const float* __restrict__ Wsv,
    float* __restrict__ score) {
  __shared__ unsigned short Al[4][128 * 32];   // 4 x 8 KiB
  __shared__ unsigned short Bl[4][512 * 32];   // 4 x 32 KiB

  const int t = threadIdx.x;
  const int lane = t & 63, w = t >> 6;
  const int frow = lane & 15, fsl = lane >> 4;
  const int row0 = (int)blockIdx.x * 128;

  // A staging: thread handles row ar, 8 floats at cols ak..ak+7 (one 16B chunk)
  const int ar = t >> 2, ak = (t & 3) * 8;
  const int abyte = ar * 64 + (((t & 3) ^ ((ar >> 1) & 3)) * 16);

  float4 rP0[2], rP1[2], rQ0[2], rQ1[2];   // four named pairs, never aliased

  auto issueA = [&](int p, float4* r) {
    const float* src = (p < 16) ? Q : K;
    const float* ap = src + (size_t)(row0 + ar) * 512 + ((p * 32) & 511) + ak;
    r[0] = *(const float4*)(ap);
    r[1] = *(const float4*)(ap + 4);
  };
  auto writeA = [&](const float4* r, int buf) {
    uint4 d;
    d.x = pk2bf(r[0].x, r[0].y);
    d.y = pk2bf(r[0].z, r[0].w);
    d.z = pk2bf(r[1].x, r[1].y);
    d.w = pk2bf(r[1].z, r[1].w);
    *(uint4*)((char*)&Al[buf][0] + abyte) = d;
  };
  auto stageB = [&](int p, int buf) {
#pragma unroll
    for (int q = 0; q < 4; ++q) {
      int pc = (w * 4 + q) * 64 + lane;        // 16B-chunk index
      int row = pc >> 2;
      int sl = (pc & 3) ^ ((row >> 1) & 3);    // inverse-swizzled source slot
      const char* g = (const char*)WT + (size_t)row * 2048 + p * 64 + sl * 16;
      gload_lds16(g, (char*)&Bl[buf][0] + (size_t)(w * 4 + q) * 1024);
    }
  };

  f32x4 acc[8][4];
#pragma unroll
  for (int m = 0; m < 8; ++m)
#pragma unroll
    for (int n = 0; n < 4; ++n) acc[m][n] = (f32x4){0.f, 0.f, 0.f, 0.f};

  const int ch = (fsl ^ ((frow >> 1) & 3)) * 16;

  auto doMfma = [&](int buf) {
    bf16x8 af[8], bfr[4];
#pragma unroll
    for (int m = 0; m < 8; ++m)
      af[m] = *(const bf16x8*)((const char*)&Al[buf][0] + (m * 16 + frow) * 64 + ch);
#pragma unroll
    for (int n = 0; n < 4; ++n)
      bfr[n] = *(const bf16x8*)((const char*)&Bl[buf][0] + (w * 64 + n * 16 + frow) * 64 + ch);
    __builtin_amdgcn_s_setprio(1);
#pragma unroll
    for (int m = 0; m < 8; ++m)
#pragma unroll
      for (int n = 0; n < 4; ++n)
        acc[m][n] = __builtin_amdgcn_mfma_f32_16x16x32_bf16(af[m], bfr[n], acc[m][n], 0, 0, 0);
    __builtin_amdgcn_s_setprio(0);
  };

  // ---- prologue: steps 0,1 into slots 0,1; A(2),A(3) left in flight ----
  issueA(0, rP0);
  issueA(1, rP1);
  stageB(0, 0);
  stageB(1, 1);
  __builtin_amdgcn_sched_barrier(0);
  writeA(rP0, 0);                       // compiler waits A(0),A(1) loads
  writeA(rP1, 1);
  issueA(2, rQ0);
  issueA(3, rQ1);
  asm volatile("s_waitcnt vmcnt(4) lgkmcnt(0)" ::: "memory");
  __builtin_amdgcn_s_barrier();

  // ---- one barrier period: compute steps {2i,2i+1}, stage {2i+2,2i+3},
  //      issue A loads for {2i+4,2i+5} into the free pair (Xa,Xb) ----
  auto period = [&](int i, const float4* Ya, const float4* Yb,
                    float4* Xa, float4* Xb, bool last) {
    const int cur2 = (i & 1) * 2, nxt2 = ((i + 1) & 1) * 2;
    stageB(2 * i + 2, nxt2);
    stageB(2 * i + 3, nxt2 + 1);
    __builtin_amdgcn_sched_barrier(0);
    if (!last) {
      issueA(2 * i + 4, Xa);
      issueA(2 * i + 5, Xb);
    }
    doMfma(cur2);
    doMfma(cur2 + 1);
    writeA(Ya, nxt2);                   // A(2i+2), A(2i+3) — write-late
    writeA(Yb, nxt2 + 1);
    if (!last)
      asm volatile("s_waitcnt vmcnt(4) lgkmcnt(0)" ::: "memory");
    else
      asm volatile("s_waitcnt vmcnt(0) lgkmcnt(0)" ::: "memory");
    __builtin_amdgcn_s_barrier();
  };

  // periods 0..13 (role alternation is static: even Y=rQ, odd Y=rP)
  for (int ii = 0; ii < 7; ++ii) {
    period(2 * ii,     rQ0, rQ1, rP0, rP1, false);
    period(2 * ii + 1, rP0, rP1, rQ0, rQ1, false);
  }
  // period 14 (even): computes steps 28,29; writes A(30),A(31); drains all
  period(14, rQ0, rQ1, rP0, rP1, true);

  // ---- tail period 15: compute steps 30,31 from slots 2,3 ----
  doMfma(2);
  doMfma(3);

  // ---- epilogue: tanh * Ws, reduce over all 512 cols ----
  // (scw aliases Al[0..1]; tail reads only Al[2..3]/Bl[2..3] — disjoint.)
  float wsv[4];
#pragma unroll
  for (int n = 0; n < 4; ++n) wsv[n] = Wsv[w * 64 + n * 16 + frow];
  float* scw = (float*)&Al[0][0];       // [8][128]
#pragma unroll
  for (int m = 0; m < 8; ++m) {
#pragma unroll
    for (int ii = 0; ii < 4; ++ii) {
      float s = 0.f;
#pragma unroll
      for (int n = 0; n < 4; ++n)
        s += fast_tanh(acc[m][n][ii]) * wsv[n];
      s += __shfl_xor(s, 1);
      s += __shfl_xor(s, 2);
      s += __shfl_xor(s, 4);
      s += __shfl_xor(s, 8);
      if (frow == 0) scw[w * 128 + m * 16 + fsl * 4 + ii] = s;
    }
  }
  __syncthreads();
  if (t < 128) {
    float s = 0.f;
#pragma unroll
    for (int ww = 0; ww < 8; ++ww) s += scw[ww * 128 + t];
    score[row0 + t] = s;
  }
}

// ---------------------------------------------------------------------------
// K3 (fused softmax + V-weighted sum): block (dh, sc, b) re-derives the
// batch softmax from the L2-hot score row, then computes
// upart[sc][b][dh-half]; dh==0 blocks write outw.
// ---------------------------------------------------------------------------
__global__ __launch_bounds__(256) void k3_vsum(const float* __restrict__ value,
                                               const float* __restrict__ score,
                                               float* __restrict__ upart,
                                               float* __restrict__ outw) {
  int bid = blockIdx.x;
  int dh = bid & 1, sc = (bid >> 1) & 15, b = bid >> 5;
  int t = threadIdx.x;
  int lane = t & 63, wave = t >> 6;
  int dg = t & 63, sg = t >> 6;
  __shared__ float red[4], red2[4];
  __shared__ float wl[128];
  __shared__ f32x4 redv[4][64];

  float v[8];
  float mx = -1e30f;
#pragma unroll
  for (int e = 0; e < 8; ++e) {
    float p = score[(size_t)b * S_ + e * 256 + t];
    v[e] = p;
    mx = fmaxf(mx, p);
  }
  for (int off = 1; off < 64; off <<= 1) mx = fmaxf(mx, __shfl_xor(mx, off));
  if (lane == 0) red[wave] = mx;
  __syncthreads();
  mx = fmaxf(fmaxf(red[0], red[1]), fmaxf(red[2], red[3]));
  float sum = 0.f;
#pragma unroll
  for (int e = 0; e < 8; ++e) sum += expf(v[e] - mx);
  for (int off = 1; off < 64; off <<= 1) sum += __shfl_xor(sum, off);
  if (lane == 0) red2[wave] = sum;
  __syncthreads();
  sum = red2[0] + red2[1] + red2[2] + red2[3];
  float inv = 1.f / sum;

  int s0 = sc * 128;
  if (t < 128) {
    size_t o = (size_t)b * S_ + s0 + t;
    float ww = expf(score[o] - mx) * inv;
    wl[t] = ww;
    if (dh == 0) outw[o] = ww;
  }
  __syncthreads();

  const float* vp = value + ((size_t)b * S_ + s0) * 512 + dh * 256 + dg * 4;
  f32x4 a = (f32x4){0.f, 0.f, 0.f, 0.f};
  for (int s = sg; s < 128; s += 4) {
    float4 v4 = *(const float4*)(vp + (size_t)s * 512);
    float ws = wl[s];
    a[0] += ws * v4.x; a[1] += ws * v4.y; a[2] += ws * v4.z; a[3] += ws * v4.w;
  }
  redv[sg][dg] = a;
  __syncthreads();
  if (sg == 0) {
    f32x4 r = redv[0][dg] + redv[1][dg] + redv[2][dg] + redv[3][dg];
    float* dst = upart + (size_t)(sc * 16 + b) * 512 + dh * 256 + dg * 4;
    dst[0] = r[0]; dst[1] = r[1]; dst[2] = r[2]; dst[3] = r[3];
  }
}

// ---------------------------------------------------------------------------
// K4: context[b,a] = sum_d u[b,d] * Wv[d,a]. fp32. 64 blocks.
// ---------------------------------------------------------------------------
__global__ __launch_bounds__(256) void k4_ctx(const float* __restrict__ upart,
                                              const float* __restrict__ Wv,
                                              float* __restrict__ out) {
  int b = blockIdx.x >> 2, q = blockIdx.x & 3;
  int t = threadIdx.x;
  int col = q * 128 + (t & 127), dhf = t >> 7;
  __shared__ float ul[512];
  __shared__ float part[2][128];
  for (int i = t; i < 512; i += 256) {
    float u = 0.f;
#pragma unroll
    for (int c = 0; c < 16; ++c) u += upart[(size_t)(c * 16 + b) * 512 + i];
    ul[i] = u;
  }
  __syncthreads();
  float acc = 0.f;
#pragma unroll 8
  for (int d = dhf * 256; d < dhf * 256 + 256; ++d)
    acc += ul[d] * Wv[(size_t)d * 512 + col];
  part[dhf][t & 127] = acc;
  __syncthreads();
  if (dhf == 0)
    out[(size_t)b * 512 + col] = part[0][t & 127] + part[1][t & 127];
}

// ---------------------------------------------------------------------------
extern "C" void kernel_launch(void* const* d_in, const int* in_sizes, int n_in,
                              void* d_out, int out_size, void* d_ws, size_t ws_size,
                              hipStream_t stream) {
  const float* Q  = (const float*)d_in[0];
  const float* Kk = (const float*)d_in[1];
  const float* V  = (const float*)d_in[2];
  const float* Wq = (const float*)d_in[3];
  const float* Wk = (const float*)d_in[4];
  const float* Wv = (const float*)d_in[5];
  const float* Ws = (const float*)d_in[6];
  float* out = (float*)d_out;

  char* ws = (char*)d_ws;
  unsigned short* WT = (unsigned short*)ws;                        // 1 MiB
  float* score = (float*)(ws + (1 << 20));                         // 128 KiB
  float* upart = (float*)(ws + (1 << 20) + (512 << 10));           // 512 KiB

  float* outw = out + B_ * A_;   // attention weights region [B*S]

  k0_pack_w<<<dim3(128), dim3(256), 0, stream>>>(Wq, Wk, WT);
  k1_scores<<<dim3(256), dim3(512), 0, stream>>>(Q, Kk, WT, Ws, score);
  k3_vsum<<<dim3(512), dim3(256), 0, stream>>>(V, score, upart, outw);
  k4_ctx<<<dim3(64), dim3(256), 0, stream>>>(upart, Wv, out);
}